// Round 13
// baseline (172.158 us; speedup 1.0000x reference)
//
#include <hip/hip_runtime.h>
#include <math.h>

#define KSIZE 31
#define HRAD 15

#define QSCALE (1023.0f / 0.75f)
#define QINV   (0.75f / 1023.0f)
#define QOFF   0.25f

// ---------------------------------------------------------------------------
// 10-bit fixed-point RGB pack/unpack (range [-0.25, 0.5])
// ---------------------------------------------------------------------------
__device__ inline unsigned quant3(float r, float g, float b) {
    int qr = (int)((r + QOFF) * QSCALE + 0.5f);
    int qg = (int)((g + QOFF) * QSCALE + 0.5f);
    int qb = (int)((b + QOFF) * QSCALE + 0.5f);
    qr = min(max(qr, 0), 1023);
    qg = min(max(qg, 0), 1023);
    qb = min(max(qb, 0), 1023);
    return (unsigned)(qr | (qg << 10) | (qb << 20));
}

__device__ inline float deqc(unsigned q, int sh) {
    return (float)((q >> sh) & 1023u) * QINV - QOFF;
}

// ---------------------------------------------------------------------------
// Cube-map coordinate math (mirrors reference cube_sample exactly, f32)
// ---------------------------------------------------------------------------
__device__ inline void cube_coords(float x, float y, float z,
                                   int& face, float& u, float& v) {
    float ax = fabsf(x), ay = fabsf(y), az = fabsf(z);
    bool is_x = (ax >= ay) && (ax >= az);
    bool is_y = (!is_x) && (ay >= az);
    float ma, sc, tc;
    if (is_x) {
        if (x >= 0.0f) { face = 0; sc = -z; } else { face = 1; sc = z; }
        ma = ax; tc = -y;
    } else if (is_y) {
        if (y >= 0.0f) { face = 2; tc = z; } else { face = 3; tc = -z; }
        ma = ay; sc = x;
    } else {
        if (z >= 0.0f) { face = 4; sc = x; } else { face = 5; sc = -x; }
        ma = az; tc = -y;
    }
    float inv = 1.0f / fmaxf(ma, 1e-12f);
    u = 0.5f * (sc * inv + 1.0f);
    v = 0.5f * (tc * inv + 1.0f);
}

// corner-record bilinear setup: corners baked; left/top edge -> wx/wy = 0
__device__ inline void nbq_setup(float u, float v, int HW, int face,
                                 int& rec, float& wx, float& wy) {
    float fx = u * (float)HW - 0.5f;
    float fy = v * (float)HW - 0.5f;
    float x0 = floorf(fx), y0 = floorf(fy);
    wx = fx - x0;
    wy = fy - y0;
    int xi = (int)x0, yi = (int)y0;
    if (xi < 0) { xi = 0; wx = 0.0f; }
    if (yi < 0) { yi = 0; wy = 0.0f; }
    rec = (face * HW + yi) * HW + xi;
}

// ---------------------------------------------------------------------------
// Inline f32 Gaussian weights (tid%128 -> lvl=(tid>>5)&3, tap=tid&31)
// ---------------------------------------------------------------------------
__device__ inline void weights_inline(int tid, float wS[4][32]) {
    const float ss[4] = {8.f, 4.f, 2.f, 1.f};
    int lvl = (tid >> 5) & 3;
    int tap = tid & 31;
    float d = (float)tap - 15.0f;
    float q = d / ss[lvl];
    float g = (tap < KSIZE) ? expf(-0.5f * q * q) : 0.0f;
    float s = g;
#pragma unroll
    for (int k = 16; k; k >>= 1) s += __shfl_xor(s, k, 32);
    if (tid < 128) wS[lvl][tap] = g / s;
}

// ---------------------------------------------------------------------------
// FUSED prep kernel (480 blocks x 256 threads):
//   blocks [0, 384)   : bg1q corner-record pack, halo-tiled (8 rows + 1 halo)
//   blocks [384, 480) : self-contained H+V 4-level blur (8 output rows) +
//                       blurq + bg0q emit.  No tmp buffer, no second launch.
// ---------------------------------------------------------------------------
__global__ __launch_bounds__(256)
void prep(const float* __restrict__ bg0, const float* __restrict__ bg1,
          uint4* __restrict__ bg0q, uint4* __restrict__ bg1q,
          uint4* __restrict__ blurq) {
    __shared__ float4 sm4[3680];          // 58,880 B
    float* sm = (float*)sm4;
    int b = blockIdx.x;
    int tid = threadIdx.x;

    if (b < 384) {
        // ---- bg1 pack: face = b/64, rows [ytile, ytile+8) ----
        int face  = b / 64;
        int ytile = (b % 64) * 8;
        // stage 9 rows (8 out + 1 halo), row index clamped to 511
        for (int i = tid; i < 9 * 384; i += 256) {   // 384 float4 per row
            int r  = i / 384;
            int c4 = i - r * 384;
            int gy = min(ytile + r, 511);
            sm4[r * 384 + c4] =
                ((const float4*)(bg1 + (size_t)(face * 512 + gy) * 1536))[c4];
        }
        __syncthreads();
#pragma unroll
        for (int i = 0; i < 16; ++i) {
            int idx = i * 256 + tid;        // 0..4095
            int yl  = idx >> 9;             // 0..7
            int x   = idx & 511;
            int x1  = min(x + 1, 511);
            const float* rA = sm + (size_t)yl * 1536;
            const float* rB = sm + (size_t)(yl + 1) * 1536;
            uint4 r;
            r.x = quant3(rA[x * 3 + 0], rA[x * 3 + 1], rA[x * 3 + 2]);
            r.y = quant3(rA[x1 * 3 + 0], rA[x1 * 3 + 1], rA[x1 * 3 + 2]);
            r.z = quant3(rB[x * 3 + 0], rB[x * 3 + 1], rB[x * 3 + 2]);
            r.w = quant3(rB[x1 * 3 + 0], rB[x1 * 3 + 1], rB[x1 * 3 + 2]);
            bg1q[(size_t)(face * 512 + ytile + yl) * 512 + x] = r;
        }
        return;
    }

    // ---- blur branch: face = bb/16, output rows [ytile, ytile+8) ----
    float (*wS)[32] = (float (*)[32])(sm + 14592);
    int bb    = b - 384;                 // 0..95
    int face  = bb / 16;
    int ytile = (bb % 16) * 8;
    int x     = tid & 127;
    int half  = tid >> 7;                // rows half*4 .. half*4+3

    weights_inline(tid, wS);

    // stage 38 raw rows: ytile-15 .. ytile+22, zero outside [0,127]
    for (int i = tid; i < 38 * 96; i += 256) {   // 96 float4 per row
        int r  = i / 96;
        int c4 = i - r * 96;
        int gy = ytile - 15 + r;
        float4 v = make_float4(0.f, 0.f, 0.f, 0.f);
        if (gy >= 0 && gy <= 127)
            v = ((const float4*)(bg0 + (size_t)(face * 128 + gy) * 384))[c4];
        sm4[r * 96 + c4] = v;
    }
    __syncthreads();

    int r0 = half * 4;
    float acc[4][12] = {};
    for (int rr = 0; rr < 34; ++rr) {
        int r = r0 + rr;                     // raw row index (0..37)
        const float* row = sm + (size_t)r * 384;
        float hv[12] = {};
        for (int t = 0; t < KSIZE; ++t) {
            int xx = x + t - HRAD;
            if (xx >= 0 && xx < 128) {
                float c0 = row[xx * 3 + 0];
                float c1 = row[xx * 3 + 1];
                float c2 = row[xx * 3 + 2];
#pragma unroll
                for (int l = 0; l < 4; ++l) {
                    float w = wS[l][t];
                    hv[l * 3 + 0] += w * c0;
                    hv[l * 3 + 1] += w * c1;
                    hv[l * 3 + 2] += w * c2;
                }
            }
        }
#pragma unroll
        for (int o = 0; o < 4; ++o) {
            int t = r - (r0 + o);            // V tap index
            if (t >= 0 && t <= 30) {
                float w0 = wS[0][t], w1 = wS[1][t], w2 = wS[2][t], w3 = wS[3][t];
                acc[o][0]  += w0 * hv[0];  acc[o][1]  += w0 * hv[1];  acc[o][2]  += w0 * hv[2];
                acc[o][3]  += w1 * hv[3];  acc[o][4]  += w1 * hv[4];  acc[o][5]  += w1 * hv[5];
                acc[o][6]  += w2 * hv[6];  acc[o][7]  += w2 * hv[7];  acc[o][8]  += w2 * hv[8];
                acc[o][9]  += w3 * hv[9];  acc[o][10] += w3 * hv[10]; acc[o][11] += w3 * hv[11];
            }
        }
    }

#pragma unroll
    for (int o = 0; o < 4; ++o) {
        int yl = r0 + o;                     // local output row 0..7
        int y  = ytile + yl;                 // absolute row
        uint4 q;
        q.x = quant3(acc[o][0], acc[o][1], acc[o][2]);
        q.y = quant3(acc[o][3], acc[o][4], acc[o][5]);
        q.z = quant3(acc[o][6], acc[o][7], acc[o][8]);
        q.w = quant3(acc[o][9], acc[o][10], acc[o][11]);
        blurq[(size_t)(face * 128 + y) * 128 + x] = q;

        // bg0 corner record from raw rows y (raw idx 15+yl) and min(y+1,127)
        const float* rowY  = sm + (size_t)(15 + yl) * 384;
        int yl1 = (y < 127) ? (15 + yl + 1) : (15 + yl);
        const float* rowY1 = sm + (size_t)yl1 * 384;
        int x1 = min(x + 1, 127);
        uint4 p;
        p.x = quant3(rowY[x * 3 + 0],  rowY[x * 3 + 1],  rowY[x * 3 + 2]);
        p.y = quant3(rowY[x1 * 3 + 0], rowY[x1 * 3 + 1], rowY[x1 * 3 + 2]);
        p.z = quant3(rowY1[x * 3 + 0],  rowY1[x * 3 + 1],  rowY1[x * 3 + 2]);
        p.w = quant3(rowY1[x1 * 3 + 0], rowY1[x1 * 3 + 1], rowY1[x1 * 3 + 2]);
        bg0q[(size_t)(face * 128 + y) * 128 + x] = p;
    }
}

// ---------------------------------------------------------------------------
// Per-ray shading (r12-proven, byte-identical)
// ---------------------------------------------------------------------------
__device__ inline void shade_one(float x, float y, float z, float sa,
                                 const uint4* __restrict__ bg0q,
                                 const uint4* __restrict__ bg1q,
                                 const uint4* __restrict__ blurq,
                                 float* __restrict__ R) {
    int face; float u, v;
    cube_coords(x, y, z, face, u, v);

    const float saTexel = (float)(4.0 * M_PI / (6.0 * 512.0 * 512.0));
    float m = logf(sa / saTexel);
    m = m / 1.3862943611198906f;   // f32(log(4))
    m = m * 0.5f;
    m = fminf(fmaxf(m, 0.0f), 3.0f);

    if (m >= 2.0f) {
        float fx = u * 128.0f - 0.5f;
        float fy = v * 128.0f - 0.5f;
        float xf = floorf(fx), yf = floorf(fy);
        float wx = fx - xf, wy = fy - yf;
        int x0i = min(max((int)xf, 0), 127);
        int x1i = min(max((int)xf + 1, 0), 127);
        int y0i = min(max((int)yf, 0), 127);
        int y1i = min(max((int)yf + 1, 0), 127);
        int base = face << 14;
        uint4 q00 = blurq[base + y0i * 128 + x0i];
        uint4 q10 = blurq[base + y0i * 128 + x1i];
        uint4 q01 = blurq[base + y1i * 128 + x0i];
        uint4 q11 = blurq[base + y1i * 128 + x1i];

        float w0 = 1.0f - fminf(fabsf(3.0f - m), 1.0f);
        float w1 = 1.0f - fminf(fabsf(2.5f - m), 1.0f);
        float w2 = 1.0f - fminf(fabsf(2.0f - m), 1.0f);
        float w3 = 1.0f - fminf(fabsf(1.5f - m), 1.0f);
        float inv = 1.0f / fmaxf(w0 + w1 + w2 + w3, 1e-8f);

#pragma unroll
        for (int c = 0; c < 3; ++c) {
            int sh = c * 10;
            float v00 = w0 * deqc(q00.x, sh) + w1 * deqc(q00.y, sh) +
                        w2 * deqc(q00.z, sh) + w3 * deqc(q00.w, sh);
            float v10 = w0 * deqc(q10.x, sh) + w1 * deqc(q10.y, sh) +
                        w2 * deqc(q10.z, sh) + w3 * deqc(q10.w, sh);
            float v01 = w0 * deqc(q01.x, sh) + w1 * deqc(q01.y, sh) +
                        w2 * deqc(q01.z, sh) + w3 * deqc(q01.w, sh);
            float v11 = w0 * deqc(q11.x, sh) + w1 * deqc(q11.y, sh) +
                        w2 * deqc(q11.z, sh) + w3 * deqc(q11.w, sh);
            float top = v00 * (1.0f - wx) + v10 * wx;
            float bot = v01 * (1.0f - wx) + v11 * wx;
            R[c] = (top * (1.0f - wy) + bot * wy) * inv;
        }
    } else {
        int r0; float wx0, wy0;
        nbq_setup(u, v, 128, face, r0, wx0, wy0);
        int r1; float wx1, wy1;
        nbq_setup(u, v, 512, face, r1, wx1, wy1);
        uint4 p0 = bg0q[r0];
        uint4 p1 = bg1q[r1];
#pragma unroll
        for (int c = 0; c < 3; ++c) {
            int sh = c * 10;
            float t0 = deqc(p0.x, sh) * (1.0f - wx0) + deqc(p0.y, sh) * wx0;
            float b0 = deqc(p0.z, sh) * (1.0f - wx0) + deqc(p0.w, sh) * wx0;
            float c0 = t0 * (1.0f - wy0) + b0 * wy0;
            float t1 = deqc(p1.x, sh) * (1.0f - wx1) + deqc(p1.y, sh) * wx1;
            float b1 = deqc(p1.z, sh) * (1.0f - wx1) + deqc(p1.w, sh) * wx1;
            float c1 = t1 * (1.0f - wy1) + b1 * wy1;
            R[c] = c0 + 0.5f * c1;
        }
    }
}

// ---------------------------------------------------------------------------
// Shade: 4 rays per thread, vectorized stream I/O.
// ---------------------------------------------------------------------------
__global__ __launch_bounds__(256)
void shade4(const float4* __restrict__ vd4, const float4* __restrict__ sa4,
            const uint4* __restrict__ bg0q, const uint4* __restrict__ bg1q,
            const uint4* __restrict__ blurq, float4* __restrict__ out4,
            int nquads) {
    int q = blockIdx.x * blockDim.x + threadIdx.x;
    if (q >= nquads) return;

    float4 a = vd4[3 * q + 0];
    float4 b = vd4[3 * q + 1];
    float4 c = vd4[3 * q + 2];
    float4 s = sa4[q];

    float X[4] = {a.x, a.w, b.z, c.y};
    float Y[4] = {a.y, b.x, b.w, c.z};
    float Z[4] = {a.z, b.y, c.x, c.w};
    float S[4] = {s.x, s.y, s.z, s.w};

    float R[12];
#pragma unroll
    for (int r = 0; r < 4; ++r) {
        shade_one(X[r], Y[r], Z[r], S[r], bg0q, bg1q, blurq, &R[3 * r]);
    }

    out4[3 * q + 0] = make_float4(R[0], R[1], R[2],  R[3]);
    out4[3 * q + 1] = make_float4(R[4], R[5], R[6],  R[7]);
    out4[3 * q + 2] = make_float4(R[8], R[9], R[10], R[11]);
}

// ---------------------------------------------------------------------------
extern "C" void kernel_launch(void* const* d_in, const int* in_sizes, int n_in,
                              void* d_out, int out_size, void* d_ws, size_t ws_size,
                              hipStream_t stream) {
    const float* viewdirs = (const float*)d_in[0];   // (B,3)
    const float* saSample = (const float*)d_in[1];   // (B,1)
    const float* bg0      = (const float*)d_in[2];   // (6,128,128,3)
    const float* bg1      = (const float*)d_in[3];   // (6,512,512,3)
    float* out = (float*)d_out;

    int B = in_sizes[0] / 3;          // 2097152
    int nquads = B / 4;

    // ws layout (28.2 MB):
    //   blurq : 98,304 uint4    (1.5 MB)
    //   bg0q  : 98,304 uint4    (1.5 MB)
    //   bg1q  : 1,572,864 uint4 (25.2 MB)
    uint4* blurq = (uint4*)d_ws;
    uint4* bg0q  = blurq + 98304;
    uint4* bg1q  = bg0q + 98304;

    prep<<<480, 256, 0, stream>>>(bg0, bg1, bg0q, bg1q, blurq);

    int blocks = (nquads + 255) / 256;
    shade4<<<blocks, 256, 0, stream>>>((const float4*)viewdirs,
                                       (const float4*)saSample,
                                       bg0q, bg1q, blurq,
                                       (float4*)out, nquads);
}

// Round 14
// 80.453 us; speedup vs baseline: 2.1399x; 2.1399x over previous
//
#include <hip/hip_runtime.h>
#include <hip/hip_fp16.h>
#include <math.h>

#define KSIZE 31
#define HRAD 15

#define QSCALE (1023.0f / 0.75f)
#define QINV   (0.75f / 1023.0f)
#define QOFF   0.25f

union H8U { float4 f4; __half h[8]; };

// ---------------------------------------------------------------------------
// 10-bit fixed-point RGB pack/unpack (range [-0.25, 0.5])
// ---------------------------------------------------------------------------
__device__ inline unsigned quant3(float r, float g, float b) {
    int qr = (int)((r + QOFF) * QSCALE + 0.5f);
    int qg = (int)((g + QOFF) * QSCALE + 0.5f);
    int qb = (int)((b + QOFF) * QSCALE + 0.5f);
    qr = min(max(qr, 0), 1023);
    qg = min(max(qg, 0), 1023);
    qb = min(max(qb, 0), 1023);
    return (unsigned)(qr | (qg << 10) | (qb << 20));
}

__device__ inline float deqc(unsigned q, int sh) {
    return (float)((q >> sh) & 1023u) * QINV - QOFF;
}

// ---------------------------------------------------------------------------
// Cube-map coordinate math (mirrors reference cube_sample exactly, f32)
// ---------------------------------------------------------------------------
__device__ inline void cube_coords(float x, float y, float z,
                                   int& face, float& u, float& v) {
    float ax = fabsf(x), ay = fabsf(y), az = fabsf(z);
    bool is_x = (ax >= ay) && (ax >= az);
    bool is_y = (!is_x) && (ay >= az);
    float ma, sc, tc;
    if (is_x) {
        if (x >= 0.0f) { face = 0; sc = -z; } else { face = 1; sc = z; }
        ma = ax; tc = -y;
    } else if (is_y) {
        if (y >= 0.0f) { face = 2; tc = z; } else { face = 3; tc = -z; }
        ma = ay; sc = x;
    } else {
        if (z >= 0.0f) { face = 4; sc = x; } else { face = 5; sc = -x; }
        ma = az; tc = -y;
    }
    float inv = 1.0f / fmaxf(ma, 1e-12f);
    u = 0.5f * (sc * inv + 1.0f);
    v = 0.5f * (tc * inv + 1.0f);
}

// corner-record bilinear setup: corners baked; left/top edge -> wx/wy = 0
__device__ inline void nbq_setup(float u, float v, int HW, int face,
                                 int& rec, float& wx, float& wy) {
    float fx = u * (float)HW - 0.5f;
    float fy = v * (float)HW - 0.5f;
    float x0 = floorf(fx), y0 = floorf(fy);
    wx = fx - x0;
    wy = fy - y0;
    int xi = (int)x0, yi = (int)y0;
    if (xi < 0) { xi = 0; wx = 0.0f; }
    if (yi < 0) { yi = 0; wy = 0.0f; }
    rec = (face * HW + yi) * HW + xi;
}

// ---------------------------------------------------------------------------
// Inline f32 Gaussian weights (tid%128 -> lvl=(tid>>5)&3, tap=tid&31)
// ---------------------------------------------------------------------------
__device__ inline void weights_inline(int tid, float wS[4][32]) {
    const float ss[4] = {8.f, 4.f, 2.f, 1.f};
    int lvl = (tid >> 5) & 3;
    int tap = tid & 31;
    float d = (float)tap - 15.0f;
    float q = d / ss[lvl];
    float g = (tap < KSIZE) ? expf(-0.5f * q * q) : 0.0f;
    float s = g;
#pragma unroll
    for (int k = 16; k; k >>= 1) s += __shfl_xor(s, k, 32);
    if (tid < 128) wS[lvl][tap] = g / s;
}

// ---------------------------------------------------------------------------
// k1: horizontal 4-level blur (2 rows/block, 384 blocks) + bg0q emit.
// tmpH: per 128-texel 32B f16 = {lvl0,lvl1 | lvl2,lvl3} RGB halves.
// (r12-proven structure, byte-identical math)
// ---------------------------------------------------------------------------
__global__ __launch_bounds__(256)
void hblur(const float* __restrict__ bg0, float4* __restrict__ tmpH,
           uint4* __restrict__ bg0q) {
    __shared__ float sm[1664];
    float (*rows)[2][384] = (float (*)[2][384])sm;
    float (*wS)[32] = (float (*)[32])(sm + 1536);

    int bid  = blockIdx.x;             // 0..383
    int tid  = threadIdx.x;
    int unit = tid >> 7;               // 0 or 1
    int lane = tid & 127;
    int face = bid / 64;
    int yrow = (bid % 64) * 2 + unit;

    weights_inline(tid, wS);

    int ynext = min(yrow + 1, 127);
    const float* srcA = bg0 + (size_t)(face * 128 + yrow) * 384;
    const float* srcB = bg0 + (size_t)(face * 128 + ynext) * 384;
    for (int k = lane; k < 384; k += 128) {
        rows[unit][0][k] = srcA[k];
        rows[unit][1][k] = srcB[k];
    }
    __syncthreads();

    int x = lane;
    float a[4][3] = {};
    for (int t = 0; t < KSIZE; ++t) {
        int xx = x + t - HRAD;
        if (xx >= 0 && xx < 128) {
            float r0 = rows[unit][0][xx * 3 + 0];
            float r1 = rows[unit][0][xx * 3 + 1];
            float r2 = rows[unit][0][xx * 3 + 2];
#pragma unroll
            for (int l = 0; l < 4; ++l) {
                float w = wS[l][t];
                a[l][0] += w * r0; a[l][1] += w * r1; a[l][2] += w * r2;
            }
        }
    }
    size_t idx = (size_t)(face * 128 + yrow) * 128 + x;
    H8U ta, tb;
#pragma unroll
    for (int l = 0; l < 2; ++l) {
        ta.h[l * 4 + 0] = __float2half(a[l][0]);
        ta.h[l * 4 + 1] = __float2half(a[l][1]);
        ta.h[l * 4 + 2] = __float2half(a[l][2]);
        ta.h[l * 4 + 3] = __float2half(0.0f);
        tb.h[l * 4 + 0] = __float2half(a[2 + l][0]);
        tb.h[l * 4 + 1] = __float2half(a[2 + l][1]);
        tb.h[l * 4 + 2] = __float2half(a[2 + l][2]);
        tb.h[l * 4 + 3] = __float2half(0.0f);
    }
    tmpH[idx * 2 + 0] = ta.f4;
    tmpH[idx * 2 + 1] = tb.f4;

    // bg0 corner record for (x, yrow)
    int x1 = min(x + 1, 127);
    uint4 r;
    r.x = quant3(rows[unit][0][x * 3 + 0], rows[unit][0][x * 3 + 1], rows[unit][0][x * 3 + 2]);
    r.y = quant3(rows[unit][0][x1 * 3 + 0], rows[unit][0][x1 * 3 + 1], rows[unit][0][x1 * 3 + 2]);
    r.z = quant3(rows[unit][1][x * 3 + 0], rows[unit][1][x * 3 + 1], rows[unit][1][x * 3 + 2]);
    r.w = quant3(rows[unit][1][x1 * 3 + 0], rows[unit][1][x1 * 3 + 1], rows[unit][1][x1 * 3 + 2]);
    bg0q[idx] = r;
}

// ---------------------------------------------------------------------------
// k2 (fused by block range):
//   blocks [0, 3072)    : bg1q corner-record pack, one full row per block,
//                         float4 LDS staging (no integer divisions).
//   blocks [3072, 3840) : vertical blur, level-split: thread (x=tid/2,
//                         half=tid&1) computes 2 levels from one tmpH half
//                         per tap -> 1 float4 load/tap, dense uint2 writes.
// ---------------------------------------------------------------------------
__global__ __launch_bounds__(256)
void packv(const float* __restrict__ bg1, const float4* __restrict__ tmpH,
           uint4* __restrict__ bg1q, uint2* __restrict__ blurq2) {
    __shared__ float4 sm4[768];        // 12,288 B
    int b = blockIdx.x;
    int tid = threadIdx.x;

    if (b < 3072) {
        // ---- bg1 pack: face = b>>9, row y = b&511 ----
        float* sm = (float*)sm4;
        int y    = b & 511;
        int face = b >> 9;
        int yn   = min(y + 1, 511);
        const float4* rA = (const float4*)(bg1 + (size_t)(face * 512 + y)  * 1536);
        const float4* rB = (const float4*)(bg1 + (size_t)(face * 512 + yn) * 1536);
        for (int i = tid; i < 384; i += 256) {
            sm4[i]       = rA[i];
            sm4[384 + i] = rB[i];
        }
        __syncthreads();
        const float* a  = sm;          // row y   : floats [0, 1536)
        const float* bb = sm + 1536;   // row y+1 : floats [0, 1536)
#pragma unroll
        for (int e = 0; e < 2; ++e) {
            int x  = e * 256 + tid;
            int x1 = min(x + 1, 511);
            uint4 r;
            r.x = quant3(a[x * 3 + 0],  a[x * 3 + 1],  a[x * 3 + 2]);
            r.y = quant3(a[x1 * 3 + 0], a[x1 * 3 + 1], a[x1 * 3 + 2]);
            r.z = quant3(bb[x * 3 + 0],  bb[x * 3 + 1],  bb[x * 3 + 2]);
            r.w = quant3(bb[x1 * 3 + 0], bb[x1 * 3 + 1], bb[x1 * 3 + 2]);
            bg1q[(size_t)(face * 512 + y) * 512 + x] = r;
        }
        return;
    }

    // ---- vertical blur: 768 blocks, one row each; 2 levels per thread ----
    float (*wS)[32] = (float (*)[32])sm4;
    int bb   = b - 3072;               // 0..767
    int yrow = bb & 127;
    int face = bb >> 7;

    weights_inline(tid, wS);
    __syncthreads();

    int x    = tid >> 1;
    int half = tid & 1;                // 0: levels 0,1   1: levels 2,3
    float a0 = 0.f, a1 = 0.f, a2 = 0.f, a3 = 0.f, a4 = 0.f, a5 = 0.f;
    int ylo = max(yrow - HRAD, 0);
    int yhi = min(yrow + HRAD, 127);
    for (int yy = ylo; yy <= yhi; ++yy) {
        int t = yy - yrow + HRAD;
        H8U q;
        q.f4 = tmpH[((size_t)(face * 128 + yy) * 128 + x) * 2 + half];
        float wA = wS[half * 2 + 0][t];
        float wB = wS[half * 2 + 1][t];
        a0 += wA * __half2float(q.h[0]);
        a1 += wA * __half2float(q.h[1]);
        a2 += wA * __half2float(q.h[2]);
        a3 += wB * __half2float(q.h[4]);
        a4 += wB * __half2float(q.h[5]);
        a5 += wB * __half2float(q.h[6]);
    }
    uint2 o;
    o.x = quant3(a0, a1, a2);
    o.y = quant3(a3, a4, a5);
    blurq2[((size_t)(face * 128 + yrow) * 128 + x) * 2 + half] = o;
}

// ---------------------------------------------------------------------------
// Per-ray shading (r12-proven, byte-identical)
// ---------------------------------------------------------------------------
__device__ inline void shade_one(float x, float y, float z, float sa,
                                 const uint4* __restrict__ bg0q,
                                 const uint4* __restrict__ bg1q,
                                 const uint4* __restrict__ blurq,
                                 float* __restrict__ R) {
    int face; float u, v;
    cube_coords(x, y, z, face, u, v);

    const float saTexel = (float)(4.0 * M_PI / (6.0 * 512.0 * 512.0));
    float m = logf(sa / saTexel);
    m = m / 1.3862943611198906f;   // f32(log(4))
    m = m * 0.5f;
    m = fminf(fmaxf(m, 0.0f), 3.0f);

    if (m >= 2.0f) {
        float fx = u * 128.0f - 0.5f;
        float fy = v * 128.0f - 0.5f;
        float xf = floorf(fx), yf = floorf(fy);
        float wx = fx - xf, wy = fy - yf;
        int x0i = min(max((int)xf, 0), 127);
        int x1i = min(max((int)xf + 1, 0), 127);
        int y0i = min(max((int)yf, 0), 127);
        int y1i = min(max((int)yf + 1, 0), 127);
        int base = face << 14;
        uint4 q00 = blurq[base + y0i * 128 + x0i];
        uint4 q10 = blurq[base + y0i * 128 + x1i];
        uint4 q01 = blurq[base + y1i * 128 + x0i];
        uint4 q11 = blurq[base + y1i * 128 + x1i];

        float w0 = 1.0f - fminf(fabsf(3.0f - m), 1.0f);
        float w1 = 1.0f - fminf(fabsf(2.5f - m), 1.0f);
        float w2 = 1.0f - fminf(fabsf(2.0f - m), 1.0f);
        float w3 = 1.0f - fminf(fabsf(1.5f - m), 1.0f);
        float inv = 1.0f / fmaxf(w0 + w1 + w2 + w3, 1e-8f);

#pragma unroll
        for (int c = 0; c < 3; ++c) {
            int sh = c * 10;
            float v00 = w0 * deqc(q00.x, sh) + w1 * deqc(q00.y, sh) +
                        w2 * deqc(q00.z, sh) + w3 * deqc(q00.w, sh);
            float v10 = w0 * deqc(q10.x, sh) + w1 * deqc(q10.y, sh) +
                        w2 * deqc(q10.z, sh) + w3 * deqc(q10.w, sh);
            float v01 = w0 * deqc(q01.x, sh) + w1 * deqc(q01.y, sh) +
                        w2 * deqc(q01.z, sh) + w3 * deqc(q01.w, sh);
            float v11 = w0 * deqc(q11.x, sh) + w1 * deqc(q11.y, sh) +
                        w2 * deqc(q11.z, sh) + w3 * deqc(q11.w, sh);
            float top = v00 * (1.0f - wx) + v10 * wx;
            float bot = v01 * (1.0f - wx) + v11 * wx;
            R[c] = (top * (1.0f - wy) + bot * wy) * inv;
        }
    } else {
        int r0; float wx0, wy0;
        nbq_setup(u, v, 128, face, r0, wx0, wy0);
        int r1; float wx1, wy1;
        nbq_setup(u, v, 512, face, r1, wx1, wy1);
        uint4 p0 = bg0q[r0];
        uint4 p1 = bg1q[r1];
#pragma unroll
        for (int c = 0; c < 3; ++c) {
            int sh = c * 10;
            float t0 = deqc(p0.x, sh) * (1.0f - wx0) + deqc(p0.y, sh) * wx0;
            float b0 = deqc(p0.z, sh) * (1.0f - wx0) + deqc(p0.w, sh) * wx0;
            float c0 = t0 * (1.0f - wy0) + b0 * wy0;
            float t1 = deqc(p1.x, sh) * (1.0f - wx1) + deqc(p1.y, sh) * wx1;
            float b1 = deqc(p1.z, sh) * (1.0f - wx1) + deqc(p1.w, sh) * wx1;
            float c1 = t1 * (1.0f - wy1) + b1 * wy1;
            R[c] = c0 + 0.5f * c1;
        }
    }
}

// ---------------------------------------------------------------------------
// Shade: 4 rays per thread, vectorized stream I/O.
// ---------------------------------------------------------------------------
__global__ __launch_bounds__(256)
void shade4(const float4* __restrict__ vd4, const float4* __restrict__ sa4,
            const uint4* __restrict__ bg0q, const uint4* __restrict__ bg1q,
            const uint4* __restrict__ blurq, float4* __restrict__ out4,
            int nquads) {
    int q = blockIdx.x * blockDim.x + threadIdx.x;
    if (q >= nquads) return;

    float4 a = vd4[3 * q + 0];
    float4 b = vd4[3 * q + 1];
    float4 c = vd4[3 * q + 2];
    float4 s = sa4[q];

    float X[4] = {a.x, a.w, b.z, c.y};
    float Y[4] = {a.y, b.x, b.w, c.z};
    float Z[4] = {a.z, b.y, c.x, c.w};
    float S[4] = {s.x, s.y, s.z, s.w};

    float R[12];
#pragma unroll
    for (int r = 0; r < 4; ++r) {
        shade_one(X[r], Y[r], Z[r], S[r], bg0q, bg1q, blurq, &R[3 * r]);
    }

    out4[3 * q + 0] = make_float4(R[0], R[1], R[2],  R[3]);
    out4[3 * q + 1] = make_float4(R[4], R[5], R[6],  R[7]);
    out4[3 * q + 2] = make_float4(R[8], R[9], R[10], R[11]);
}

// ---------------------------------------------------------------------------
extern "C" void kernel_launch(void* const* d_in, const int* in_sizes, int n_in,
                              void* d_out, int out_size, void* d_ws, size_t ws_size,
                              hipStream_t stream) {
    const float* viewdirs = (const float*)d_in[0];   // (B,3)
    const float* saSample = (const float*)d_in[1];   // (B,1)
    const float* bg0      = (const float*)d_in[2];   // (6,128,128,3)
    const float* bg1      = (const float*)d_in[3];   // (6,512,512,3)
    float* out = (float*)d_out;

    int B = in_sizes[0] / 3;          // 2097152
    int nquads = B / 4;

    // ws layout (31.2 MB):
    //   blurq : 98,304 uint4    (1.5 MB)
    //   bg0q  : 98,304 uint4    (1.5 MB)
    //   bg1q  : 1,572,864 uint4 (25.2 MB)
    //   tmpH  : 196,608 float4  (3.0 MB)
    uint4*  blurq = (uint4*)d_ws;
    uint4*  bg0q  = blurq + 98304;
    uint4*  bg1q  = bg0q + 98304;
    float4* tmpH  = (float4*)(bg1q + 1572864);

    hblur<<<384, 256, 0, stream>>>(bg0, tmpH, bg0q);
    packv<<<3072 + 768, 256, 0, stream>>>(bg1, tmpH, bg1q, (uint2*)blurq);

    int blocks = (nquads + 255) / 256;
    shade4<<<blocks, 256, 0, stream>>>((const float4*)viewdirs,
                                       (const float4*)saSample,
                                       bg0q, bg1q, blurq,
                                       (float4*)out, nquads);
}

// Round 16
// 78.026 us; speedup vs baseline: 2.2064x; 1.0311x over previous
//
#include <hip/hip_runtime.h>
#include <hip/hip_fp16.h>
#include <math.h>

#define KSIZE 31
#define HRAD 15

#define QSCALE (1023.0f / 0.75f)
#define QINV   (0.75f / 1023.0f)
#define QOFF   0.25f

union H8U { float4 f4; __half h[8]; };

// ---------------------------------------------------------------------------
// 10-bit fixed-point RGB pack/unpack (range [-0.25, 0.5])
// ---------------------------------------------------------------------------
__device__ inline unsigned quant3(float r, float g, float b) {
    int qr = (int)((r + QOFF) * QSCALE + 0.5f);
    int qg = (int)((g + QOFF) * QSCALE + 0.5f);
    int qb = (int)((b + QOFF) * QSCALE + 0.5f);
    qr = min(max(qr, 0), 1023);
    qg = min(max(qg, 0), 1023);
    qb = min(max(qb, 0), 1023);
    return (unsigned)(qr | (qg << 10) | (qb << 20));
}

__device__ inline float deqc(unsigned q, int sh) {
    return (float)((q >> sh) & 1023u) * QINV - QOFF;
}

// ---------------------------------------------------------------------------
// Cube-map coordinate math (mirrors reference cube_sample exactly, f32)
// ---------------------------------------------------------------------------
__device__ inline void cube_coords(float x, float y, float z,
                                   int& face, float& u, float& v) {
    float ax = fabsf(x), ay = fabsf(y), az = fabsf(z);
    bool is_x = (ax >= ay) && (ax >= az);
    bool is_y = (!is_x) && (ay >= az);
    float ma, sc, tc;
    if (is_x) {
        if (x >= 0.0f) { face = 0; sc = -z; } else { face = 1; sc = z; }
        ma = ax; tc = -y;
    } else if (is_y) {
        if (y >= 0.0f) { face = 2; tc = z; } else { face = 3; tc = -z; }
        ma = ay; sc = x;
    } else {
        if (z >= 0.0f) { face = 4; sc = x; } else { face = 5; sc = -x; }
        ma = az; tc = -y;
    }
    float inv = 1.0f / fmaxf(ma, 1e-12f);
    u = 0.5f * (sc * inv + 1.0f);
    v = 0.5f * (tc * inv + 1.0f);
}

// corner-record bilinear setup: corners baked; left/top edge -> wx/wy = 0
__device__ inline void nbq_setup(float u, float v, int HW, int face,
                                 int& rec, float& wx, float& wy) {
    float fx = u * (float)HW - 0.5f;
    float fy = v * (float)HW - 0.5f;
    float x0 = floorf(fx), y0 = floorf(fy);
    wx = fx - x0;
    wy = fy - y0;
    int xi = (int)x0, yi = (int)y0;
    if (xi < 0) { xi = 0; wx = 0.0f; }
    if (yi < 0) { yi = 0; wy = 0.0f; }
    rec = (face * HW + yi) * HW + xi;
}

// ---------------------------------------------------------------------------
// Inline f32 Gaussian weights (tid%128 -> lvl=(tid>>5)&3, tap=tid&31)
// ---------------------------------------------------------------------------
__device__ inline void weights_inline(int tid, float wS[4][32]) {
    const float ss[4] = {8.f, 4.f, 2.f, 1.f};
    int lvl = (tid >> 5) & 3;
    int tap = tid & 31;
    float d = (float)tap - 15.0f;
    float q = d / ss[lvl];
    float g = (tap < KSIZE) ? expf(-0.5f * q * q) : 0.0f;
    float s = g;
#pragma unroll
    for (int k = 16; k; k >>= 1) s += __shfl_xor(s, k, 32);
    if (tid < 128) wS[lvl][tap] = g / s;
}

// ---------------------------------------------------------------------------
// k1 (fused by block range, 768 blocks):
//   blocks [0, 384)   : bg1q pack, 8-row tile + 1 halo row staged in LDS
//                       (r13-proven pack branch; 20.7 MB reads, coalesced)
//   blocks [384, 768) : horizontal 4-level blur (2 rows/block) + bg0q emit
//                       (r14-proven hblur, byte-identical)
// ---------------------------------------------------------------------------
__global__ __launch_bounds__(256)
void prep1(const float* __restrict__ bg0, const float* __restrict__ bg1,
           float4* __restrict__ tmpH, uint4* __restrict__ bg0q,
           uint4* __restrict__ bg1q) {
    __shared__ float4 sm4[3456];       // 13,824 B
    float* sm = (float*)sm4;
    int b = blockIdx.x;
    int tid = threadIdx.x;

    if (b < 384) {
        // ---- bg1 pack: face = b/64, rows [ytile, ytile+8) ----
        int face  = b / 64;
        int ytile = (b % 64) * 8;
        for (int i = tid; i < 9 * 384; i += 256) {   // 384 float4 per row
            int r  = i / 384;
            int c4 = i - r * 384;
            int gy = min(ytile + r, 511);
            sm4[r * 384 + c4] =
                ((const float4*)(bg1 + (size_t)(face * 512 + gy) * 1536))[c4];
        }
        __syncthreads();
#pragma unroll
        for (int i = 0; i < 16; ++i) {
            int idx = i * 256 + tid;        // 0..4095
            int yl  = idx >> 9;             // 0..7
            int x   = idx & 511;
            int x1  = min(x + 1, 511);
            const float* rA = sm + (size_t)yl * 1536;
            const float* rB = sm + (size_t)(yl + 1) * 1536;
            uint4 r;
            r.x = quant3(rA[x * 3 + 0],  rA[x * 3 + 1],  rA[x * 3 + 2]);
            r.y = quant3(rA[x1 * 3 + 0], rA[x1 * 3 + 1], rA[x1 * 3 + 2]);
            r.z = quant3(rB[x * 3 + 0],  rB[x * 3 + 1],  rB[x * 3 + 2]);
            r.w = quant3(rB[x1 * 3 + 0], rB[x1 * 3 + 1], rB[x1 * 3 + 2]);
            bg1q[(size_t)(face * 512 + ytile + yl) * 512 + x] = r;
        }
        return;
    }

    // ---- hblur branch (r14 byte-identical) ----
    float (*rows)[2][384] = (float (*)[2][384])sm;
    float (*wS)[32] = (float (*)[32])(sm + 1536);

    int bid  = b - 384;                // 0..383
    int unit = tid >> 7;               // 0 or 1
    int lane = tid & 127;
    int face = bid / 64;
    int yrow = (bid % 64) * 2 + unit;

    weights_inline(tid, wS);

    int ynext = min(yrow + 1, 127);
    const float* srcA = bg0 + (size_t)(face * 128 + yrow) * 384;
    const float* srcB = bg0 + (size_t)(face * 128 + ynext) * 384;
    for (int k = lane; k < 384; k += 128) {
        rows[unit][0][k] = srcA[k];
        rows[unit][1][k] = srcB[k];
    }
    __syncthreads();

    int x = lane;
    float a[4][3] = {};
    for (int t = 0; t < KSIZE; ++t) {
        int xx = x + t - HRAD;
        if (xx >= 0 && xx < 128) {
            float r0 = rows[unit][0][xx * 3 + 0];
            float r1 = rows[unit][0][xx * 3 + 1];
            float r2 = rows[unit][0][xx * 3 + 2];
#pragma unroll
            for (int l = 0; l < 4; ++l) {
                float w = wS[l][t];
                a[l][0] += w * r0; a[l][1] += w * r1; a[l][2] += w * r2;
            }
        }
    }
    size_t idx = (size_t)(face * 128 + yrow) * 128 + x;
    H8U ta, tb;
#pragma unroll
    for (int l = 0; l < 2; ++l) {
        ta.h[l * 4 + 0] = __float2half(a[l][0]);
        ta.h[l * 4 + 1] = __float2half(a[l][1]);
        ta.h[l * 4 + 2] = __float2half(a[l][2]);
        ta.h[l * 4 + 3] = __float2half(0.0f);
        tb.h[l * 4 + 0] = __float2half(a[2 + l][0]);
        tb.h[l * 4 + 1] = __float2half(a[2 + l][1]);
        tb.h[l * 4 + 2] = __float2half(a[2 + l][2]);
        tb.h[l * 4 + 3] = __float2half(0.0f);
    }
    tmpH[idx * 2 + 0] = ta.f4;
    tmpH[idx * 2 + 1] = tb.f4;

    // bg0 corner record for (x, yrow)
    int x1 = min(x + 1, 127);
    uint4 r;
    r.x = quant3(rows[unit][0][x * 3 + 0], rows[unit][0][x * 3 + 1], rows[unit][0][x * 3 + 2]);
    r.y = quant3(rows[unit][0][x1 * 3 + 0], rows[unit][0][x1 * 3 + 1], rows[unit][0][x1 * 3 + 2]);
    r.z = quant3(rows[unit][1][x * 3 + 0], rows[unit][1][x * 3 + 1], rows[unit][1][x * 3 + 2]);
    r.w = quant3(rows[unit][1][x1 * 3 + 0], rows[unit][1][x1 * 3 + 1], rows[unit][1][x1 * 3 + 2]);
    bg0q[idx] = r;
}

// ---------------------------------------------------------------------------
// k2: vertical blur (768 blocks, one row each; 2 levels per thread)
// (r14-proven branch, byte-identical)
// ---------------------------------------------------------------------------
__global__ __launch_bounds__(256)
void vblur(const float4* __restrict__ tmpH, uint2* __restrict__ blurq2) {
    __shared__ float wS[4][32];
    int b    = blockIdx.x;             // 0..767
    int tid  = threadIdx.x;
    int yrow = b & 127;
    int face = b >> 7;

    weights_inline(tid, wS);
    __syncthreads();

    int x    = tid >> 1;
    int half = tid & 1;                // 0: levels 0,1   1: levels 2,3
    float a0 = 0.f, a1 = 0.f, a2 = 0.f, a3 = 0.f, a4 = 0.f, a5 = 0.f;
    int ylo = max(yrow - HRAD, 0);
    int yhi = min(yrow + HRAD, 127);
    for (int yy = ylo; yy <= yhi; ++yy) {
        int t = yy - yrow + HRAD;
        H8U q;
        q.f4 = tmpH[((size_t)(face * 128 + yy) * 128 + x) * 2 + half];
        float wA = wS[half * 2 + 0][t];
        float wB = wS[half * 2 + 1][t];
        a0 += wA * __half2float(q.h[0]);
        a1 += wA * __half2float(q.h[1]);
        a2 += wA * __half2float(q.h[2]);
        a3 += wB * __half2float(q.h[4]);
        a4 += wB * __half2float(q.h[5]);
        a5 += wB * __half2float(q.h[6]);
    }
    uint2 o;
    o.x = quant3(a0, a1, a2);
    o.y = quant3(a3, a4, a5);
    blurq2[((size_t)(face * 128 + yrow) * 128 + x) * 2 + half] = o;
}

// ---------------------------------------------------------------------------
// Per-ray shading (r12-proven, byte-identical)
// ---------------------------------------------------------------------------
__device__ inline void shade_one(float x, float y, float z, float sa,
                                 const uint4* __restrict__ bg0q,
                                 const uint4* __restrict__ bg1q,
                                 const uint4* __restrict__ blurq,
                                 float* __restrict__ R) {
    int face; float u, v;
    cube_coords(x, y, z, face, u, v);

    const float saTexel = (float)(4.0 * M_PI / (6.0 * 512.0 * 512.0));
    float m = logf(sa / saTexel);
    m = m / 1.3862943611198906f;   // f32(log(4))
    m = m * 0.5f;
    m = fminf(fmaxf(m, 0.0f), 3.0f);

    if (m >= 2.0f) {
        float fx = u * 128.0f - 0.5f;
        float fy = v * 128.0f - 0.5f;
        float xf = floorf(fx), yf = floorf(fy);
        float wx = fx - xf, wy = fy - yf;
        int x0i = min(max((int)xf, 0), 127);
        int x1i = min(max((int)xf + 1, 0), 127);
        int y0i = min(max((int)yf, 0), 127);
        int y1i = min(max((int)yf + 1, 0), 127);
        int base = face << 14;
        uint4 q00 = blurq[base + y0i * 128 + x0i];
        uint4 q10 = blurq[base + y0i * 128 + x1i];
        uint4 q01 = blurq[base + y1i * 128 + x0i];
        uint4 q11 = blurq[base + y1i * 128 + x1i];

        float w0 = 1.0f - fminf(fabsf(3.0f - m), 1.0f);
        float w1 = 1.0f - fminf(fabsf(2.5f - m), 1.0f);
        float w2 = 1.0f - fminf(fabsf(2.0f - m), 1.0f);
        float w3 = 1.0f - fminf(fabsf(1.5f - m), 1.0f);
        float inv = 1.0f / fmaxf(w0 + w1 + w2 + w3, 1e-8f);

#pragma unroll
        for (int c = 0; c < 3; ++c) {
            int sh = c * 10;
            float v00 = w0 * deqc(q00.x, sh) + w1 * deqc(q00.y, sh) +
                        w2 * deqc(q00.z, sh) + w3 * deqc(q00.w, sh);
            float v10 = w0 * deqc(q10.x, sh) + w1 * deqc(q10.y, sh) +
                        w2 * deqc(q10.z, sh) + w3 * deqc(q10.w, sh);
            float v01 = w0 * deqc(q01.x, sh) + w1 * deqc(q01.y, sh) +
                        w2 * deqc(q01.z, sh) + w3 * deqc(q01.w, sh);
            float v11 = w0 * deqc(q11.x, sh) + w1 * deqc(q11.y, sh) +
                        w2 * deqc(q11.z, sh) + w3 * deqc(q11.w, sh);
            float top = v00 * (1.0f - wx) + v10 * wx;
            float bot = v01 * (1.0f - wx) + v11 * wx;
            R[c] = (top * (1.0f - wy) + bot * wy) * inv;
        }
    } else {
        int r0; float wx0, wy0;
        nbq_setup(u, v, 128, face, r0, wx0, wy0);
        int r1; float wx1, wy1;
        nbq_setup(u, v, 512, face, r1, wx1, wy1);
        uint4 p0 = bg0q[r0];
        uint4 p1 = bg1q[r1];
#pragma unroll
        for (int c = 0; c < 3; ++c) {
            int sh = c * 10;
            float t0 = deqc(p0.x, sh) * (1.0f - wx0) + deqc(p0.y, sh) * wx0;
            float b0 = deqc(p0.z, sh) * (1.0f - wx0) + deqc(p0.w, sh) * wx0;
            float c0 = t0 * (1.0f - wy0) + b0 * wy0;
            float t1 = deqc(p1.x, sh) * (1.0f - wx1) + deqc(p1.y, sh) * wx1;
            float b1 = deqc(p1.z, sh) * (1.0f - wx1) + deqc(p1.w, sh) * wx1;
            float c1 = t1 * (1.0f - wy1) + b1 * wy1;
            R[c] = c0 + 0.5f * c1;
        }
    }
}

// ---------------------------------------------------------------------------
// Shade: 4 rays per thread, vectorized stream I/O.
// ---------------------------------------------------------------------------
__global__ __launch_bounds__(256)
void shade4(const float4* __restrict__ vd4, const float4* __restrict__ sa4,
            const uint4* __restrict__ bg0q, const uint4* __restrict__ bg1q,
            const uint4* __restrict__ blurq, float4* __restrict__ out4,
            int nquads) {
    int q = blockIdx.x * blockDim.x + threadIdx.x;
    if (q >= nquads) return;

    float4 a = vd4[3 * q + 0];
    float4 b = vd4[3 * q + 1];
    float4 c = vd4[3 * q + 2];
    float4 s = sa4[q];

    float X[4] = {a.x, a.w, b.z, c.y};
    float Y[4] = {a.y, b.x, b.w, c.z};
    float Z[4] = {a.z, b.y, c.x, c.w};
    float S[4] = {s.x, s.y, s.z, s.w};

    float R[12];
#pragma unroll
    for (int r = 0; r < 4; ++r) {
        shade_one(X[r], Y[r], Z[r], S[r], bg0q, bg1q, blurq, &R[3 * r]);
    }

    out4[3 * q + 0] = make_float4(R[0], R[1], R[2],  R[3]);
    out4[3 * q + 1] = make_float4(R[4], R[5], R[6],  R[7]);
    out4[3 * q + 2] = make_float4(R[8], R[9], R[10], R[11]);
}

// ---------------------------------------------------------------------------
extern "C" void kernel_launch(void* const* d_in, const int* in_sizes, int n_in,
                              void* d_out, int out_size, void* d_ws, size_t ws_size,
                              hipStream_t stream) {
    const float* viewdirs = (const float*)d_in[0];   // (B,3)
    const float* saSample = (const float*)d_in[1];   // (B,1)
    const float* bg0      = (const float*)d_in[2];   // (6,128,128,3)
    const float* bg1      = (const float*)d_in[3];   // (6,512,512,3)
    float* out = (float*)d_out;

    int B = in_sizes[0] / 3;          // 2097152
    int nquads = B / 4;

    // ws layout (31.2 MB):
    //   blurq : 98,304 uint4    (1.5 MB)
    //   bg0q  : 98,304 uint4    (1.5 MB)
    //   bg1q  : 1,572,864 uint4 (25.2 MB)
    //   tmpH  : 196,608 float4  (3.0 MB)
    uint4*  blurq = (uint4*)d_ws;
    uint4*  bg0q  = blurq + 98304;
    uint4*  bg1q  = bg0q + 98304;
    float4* tmpH  = (float4*)(bg1q + 1572864);

    prep1<<<768, 256, 0, stream>>>(bg0, bg1, tmpH, bg0q, bg1q);
    vblur<<<768, 256, 0, stream>>>(tmpH, (uint2*)blurq);

    int blocks = (nquads + 255) / 256;
    shade4<<<blocks, 256, 0, stream>>>((const float4*)viewdirs,
                                       (const float4*)saSample,
                                       bg0q, bg1q, blurq,
                                       (float4*)out, nquads);
}